// Round 1
// 7401.624 us; speedup vs baseline: 1.0326x; 1.0326x over previous
//
#include <hip/hip_runtime.h>
#include <hip/hip_bf16.h>
#include <hip/hip_cooperative_groups.h>
#include <stdint.h>

namespace cg = cooperative_groups;

typedef __hip_bfloat16 bf16;
typedef __attribute__((ext_vector_type(8))) short s16x8;
typedef __attribute__((ext_vector_type(4))) float f32x4;

#define MFMA_BF16 __builtin_amdgcn_mfma_f32_16x16x32_bf16

// T=128, B=128, H=1024, I=2048. M = T*B = 16384. Gate order i,f,g,o.
// ALL d_in / d_out storage is FLOAT32 (values bf16-quantized by harness).
//
// Workspace layout:
//   WHH6b  bf16 [4096][1024] @ 0           ( 8,388,608 B)
//   WHH10b bf16 [4096][1024] @  8,388,608  ( 8,388,608 B)
//   OUT7b  bf16 [16384][1024] @ 16,777,216 (33,554,432 B)  h1 history (bf16)
//   ZERO   bf16 [131072]     @ 50,331,648  (   262,144 B)
//   H2A    bf16 [131072]     @ 50,593,792  (   262,144 B)
//   H2B    bf16 [131072]     @ 50,855,936  (   262,144 B)
//   C1     f32  [131072]     @ 51,118,080  (   524,288 B)
//   C2     f32  [131072]     @ 51,642,368  (   524,288 B)
//   Xc     f32  [TC*128][4096] @ 52,166,656 (TC*2,097,152 B; TC adaptive)
//   IN0b/IN4b/WIHb bf16 after Xc (32M+32M+16M, only if ws allows: use_bf)

__device__ __forceinline__ float sigmoidf_(float x) {
  return 1.0f / (1.0f + __expf(-x));
}
__device__ __forceinline__ float tanhf_(float x) {
  return 2.0f / (1.0f + __expf(-2.0f * x)) - 1.0f;
}

__device__ __forceinline__ s16x8 cvt8(const float* __restrict__ p) {
  s16x8 r;
#pragma unroll
  for (int i = 0; i < 8; i++) {
    bf16 h = __float2bfloat16(p[i]);   // exact: values are bf16-grid
    r[i] = *(const short*)&h;
  }
  return r;
}

// f32 -> bf16 bulk convert; each thread does 8 elements.
__global__ __launch_bounds__(256)
void cvt_k(const float* __restrict__ src, bf16* __restrict__ dst) {
  const size_t i = (size_t)(blockIdx.x * 256 + threadIdx.x) * 8;
  *(s16x8*)(dst + i) = cvt8(src + i);
}

// X[m][n] = sum_k concat(A0,A1)[row_base+m][k] * W[n][k] + b0[n] + b1[n]
// A0/A1: [16384][1024]; W: [4096][2048]. Each operand bf16 (flag=1) or f32.
// X: [TC*128][4096] f32. grid = (32, TC), block 256.
__global__ __launch_bounds__(256)
void gemm_xp(const void* __restrict__ A0, int a0_bf,
             const void* __restrict__ A1, int a1_bf,
             const void* __restrict__ W, int w_bf,
             const float* __restrict__ b0, const float* __restrict__ b1,
             float* __restrict__ X, int row_base)
{
  __shared__ short As[128][32];
  __shared__ short Bs[128][32];
  const int tid = threadIdx.x;
  const int wave = tid >> 6, lane = tid & 63;
  const int lr = lane & 15, lq = lane >> 4;
  const int wm = wave >> 1, wn = wave & 1;
  const int lrow0 = blockIdx.y * 128;          // local row in chunk
  const int grow0 = row_base + lrow0;          // global row in [0,16384)
  const int col0 = blockIdx.x * 128;

  f32x4 acc[4][4];
  const f32x4 z = {0.f, 0.f, 0.f, 0.f};
  for (int i = 0; i < 4; i++)
    for (int j = 0; j < 4; j++) acc[i][j] = z;

  const int sr = tid >> 2;            // 0..63
  const int skk = (tid & 3) * 8;      // 0,8,16,24

  for (int k0 = 0; k0 < 2048; k0 += 32) {
    if (k0 < 1024) {
      if (a0_bf) {
        const bf16* Ab = (const bf16*)A0;
        *(s16x8*)&As[sr][skk]      = *(const s16x8*)(Ab + (size_t)(grow0 + sr) * 1024 + k0 + skk);
        *(s16x8*)&As[sr + 64][skk] = *(const s16x8*)(Ab + (size_t)(grow0 + sr + 64) * 1024 + k0 + skk);
      } else {
        const float* Af = (const float*)A0;
        *(s16x8*)&As[sr][skk]      = cvt8(Af + (size_t)(grow0 + sr) * 1024 + k0 + skk);
        *(s16x8*)&As[sr + 64][skk] = cvt8(Af + (size_t)(grow0 + sr + 64) * 1024 + k0 + skk);
      }
    } else {
      const int ac = k0 - 1024;
      if (a1_bf) {
        const bf16* Ab = (const bf16*)A1;
        *(s16x8*)&As[sr][skk]      = *(const s16x8*)(Ab + (size_t)(grow0 + sr) * 1024 + ac + skk);
        *(s16x8*)&As[sr + 64][skk] = *(const s16x8*)(Ab + (size_t)(grow0 + sr + 64) * 1024 + ac + skk);
      } else {
        const float* Af = (const float*)A1;
        *(s16x8*)&As[sr][skk]      = cvt8(Af + (size_t)(grow0 + sr) * 1024 + ac + skk);
        *(s16x8*)&As[sr + 64][skk] = cvt8(Af + (size_t)(grow0 + sr + 64) * 1024 + ac + skk);
      }
    }
    if (w_bf) {
      const bf16* Wb = (const bf16*)W;
      *(s16x8*)&Bs[sr][skk]      = *(const s16x8*)(Wb + (size_t)(col0 + sr) * 2048 + k0 + skk);
      *(s16x8*)&Bs[sr + 64][skk] = *(const s16x8*)(Wb + (size_t)(col0 + sr + 64) * 2048 + k0 + skk);
    } else {
      const float* Wf = (const float*)W;
      *(s16x8*)&Bs[sr][skk]      = cvt8(Wf + (size_t)(col0 + sr) * 2048 + k0 + skk);
      *(s16x8*)&Bs[sr + 64][skk] = cvt8(Wf + (size_t)(col0 + sr + 64) * 2048 + k0 + skk);
    }
    __syncthreads();
    s16x8 bfrag[4];
    for (int nt = 0; nt < 4; nt++)
      bfrag[nt] = *(const s16x8*)&Bs[wn * 64 + nt * 16 + lr][lq * 8];
    for (int mt = 0; mt < 4; mt++) {
      s16x8 a = *(const s16x8*)&As[wm * 64 + mt * 16 + lr][lq * 8];
      for (int nt = 0; nt < 4; nt++)
        acc[mt][nt] = MFMA_BF16(a, bfrag[nt], acc[mt][nt], 0, 0, 0);
    }
    __syncthreads();
  }

  for (int mt = 0; mt < 4; mt++) {
    const int mbase = lrow0 + wm * 64 + mt * 16 + lq * 4;   // local row
    for (int nt = 0; nt < 4; nt++) {
      const int n = col0 + wn * 64 + nt * 16 + lr;
      const float bias = b0[n] + b1[n];
      for (int r = 0; r < 4; r++)
        X[(size_t)(mbase + r) * 4096 + n] = acc[mt][nt][r] + bias;
    }
  }
}

// Persistent cooperative LSTM chunk: TC timesteps, grid.sync() between steps.
// grid = 128 blocks (bid&63 = j-tile of 16 cols, bid>>6 = batch half of 64 rows),
// block = 256 threads (4 waves x 16 rows). Per block: its 64 w_hh rows
// (4 gates x 16 cols, K=1024) live in 128 KB LDS, XOR-swizzled so the
// stride-2048B ds_read_b128 is conflict-free. c lives in 4 registers/thread
// across the whole chunk (loaded/stored once per launch).
__global__ __launch_bounds__(256, 1)
void lstm_chunk(const bf16* __restrict__ w_hh,      // [4096][1024] bf16
                const float* __restrict__ xp,       // [TC*128][4096] f32
                float* __restrict__ c_g,            // [128][1024] f32
                bf16* __restrict__ hist,            // layer1: OUT7b history
                bf16* __restrict__ h2a, bf16* __restrict__ h2b, // layer2 dbuf
                const bf16* __restrict__ zero,
                const bf16* __restrict__ add_base,  // layer2: OUT7b
                float* __restrict__ o11, float* __restrict__ o14,
                int t0, int nsteps, int layer2)
{
  __shared__ __align__(16) char WS[131072];
  const int tid = threadIdx.x;
  const int wave = tid >> 6, lane = tid & 63;
  const int lr = lane & 15, lq = lane >> 4;
  const int jb = blockIdx.x & 63, mb = blockIdx.x >> 6;
  const int j0 = jb * 16;
  const int rowb = mb * 64 + wave * 16;

  // Stage w_hh slice: LDS row rr = gate*16 + col holds w_hh[gate*1024+j0+col][:].
  // Swizzle: byte ^= (rr&7)<<4 (write and read sides identical).
  for (int i = tid; i < 8192; i += 256) {
    const int rr = i >> 7, ck = i & 127;          // 64 rows x 128 16B-chunks
    const int g = rr >> 4, col = rr & 15;
    const s16x8 v = *(const s16x8*)(w_hh + ((size_t)(g * 1024 + j0 + col) << 10) + (ck << 3));
    *(s16x8*)(WS + (((rr << 11) + (ck << 4)) ^ ((rr & 7) << 4))) = v;
  }

  const int j = j0 + lr;
  const int b0r = rowb + lq * 4;
  float creg[4];
#pragma unroll
  for (int r = 0; r < 4; r++) creg[r] = c_g[(b0r + r) * 1024 + j];

  const int sw = (lr & 7) << 4;
  const int rb0 = lr << 11;                 // gate i rows
  const int rb1 = (16 + lr) << 11;          // gate f
  const int rb2 = (32 + lr) << 11;          // gate g
  const int rb3 = (48 + lr) << 11;          // gate o

  cg::grid_group grid = cg::this_grid();
  __syncthreads();

  for (int tt = 0; tt < nsteps; ++tt) {
    const int t = t0 + tt;
    const bf16* hp;
    bf16* hn;
    if (layer2) {
      hp = (t == 0) ? zero : ((t & 1) ? h2a : h2b);
      hn = (t & 1) ? h2b : h2a;
    } else {
      hp = (t == 0) ? zero : (hist + ((size_t)(t - 1) << 17));
      hn = hist + ((size_t)t << 17);
    }

    f32x4 acc[4];
    const f32x4 z = {0.f, 0.f, 0.f, 0.f};
    acc[0] = z; acc[1] = z; acc[2] = z; acc[3] = z;

    const bf16* ap = hp + ((size_t)(rowb + lr) << 10) + lq * 8;
#pragma unroll 8
    for (int k0 = 0; k0 < 1024; k0 += 32) {
      const s16x8 a = *(const s16x8*)(ap + k0);
      const int co = (((k0 >> 3) + lq) << 4) ^ sw;
      acc[0] = MFMA_BF16(a, *(const s16x8*)(WS + rb0 + co), acc[0], 0, 0, 0);
      acc[1] = MFMA_BF16(a, *(const s16x8*)(WS + rb1 + co), acc[1], 0, 0, 0);
      acc[2] = MFMA_BF16(a, *(const s16x8*)(WS + rb2 + co), acc[2], 0, 0, 0);
      acc[3] = MFMA_BF16(a, *(const s16x8*)(WS + rb3 + co), acc[3], 0, 0, 0);
    }

    const float* xpt = xp + ((size_t)tt << 19);
#pragma unroll
    for (int r = 0; r < 4; r++) {
      const int b = b0r + r;
      const float gi = acc[0][r] + xpt[b * 4096 + j];
      const float gf = acc[1][r] + xpt[b * 4096 + 1024 + j];
      const float gg = acc[2][r] + xpt[b * 4096 + 2048 + j];
      const float go = acc[3][r] + xpt[b * 4096 + 3072 + j];
      const float i_ = sigmoidf_(gi);
      const float f_ = sigmoidf_(gf);
      const float g_ = tanhf_(gg);
      const float o_ = sigmoidf_(go);
      const float cn = f_ * creg[r] + i_ * g_;
      creg[r] = cn;
      const float hv = o_ * tanhf_(cn);
      const int idx = b * 1024 + j;
      hn[idx] = __float2bfloat16(hv);
      if (layer2) {
        const float ov = hv + __bfloat162float(add_base[((size_t)t << 17) + idx]);
        o11[((size_t)t << 17) + idx] = ov;          // out11[t] (f32)
        o14[((size_t)t << 18) + b * 2048 + j] = ov; // out14[t][:, 0:1024]
      }
    }

    if (tt + 1 < nsteps) grid.sync();   // h/c(t) visible before step t+1
  }

#pragma unroll
  for (int r = 0; r < 4; r++) c_g[(b0r + r) * 1024 + j] = creg[r];
}

// out1 = input4 (f32 copy); out14[:, :, 1024:2048] = input4
__global__ __launch_bounds__(256)
void finalize_k(const float4* __restrict__ in4, float4* __restrict__ out1,
                float* __restrict__ out14)
{
  const int ci = blockIdx.x * 256 + threadIdx.x;   // 4,194,304 chunks of 4 f32
  float4 v = in4[ci];
  out1[ci] = v;
  const int flat = ci * 4;
  const int row = flat >> 10, j = flat & 1023;
  *(float4*)&out14[(size_t)row * 2048 + 1024 + j] = v;
}

extern "C" void kernel_launch(void* const* d_in, const int* in_sizes, int n_in,
                              void* d_out, int out_size, void* d_ws, size_t ws_size,
                              hipStream_t stream)
{
  const float* input4 = (const float*)d_in[0];
  const float* input0 = (const float*)d_in[1];
  const float* w_ih6  = (const float*)d_in[2];
  const float* w_hh6  = (const float*)d_in[3];
  const float* b_ih6  = (const float*)d_in[4];
  const float* b_hh6  = (const float*)d_in[5];
  const float* w_ih10 = (const float*)d_in[6];
  const float* w_hh10 = (const float*)d_in[7];
  const float* b_ih10 = (const float*)d_in[8];
  const float* b_hh10 = (const float*)d_in[9];

  char* ws = (char*)d_ws;
  bf16* WHH6b  = (bf16*)(ws);                       //  8,388,608 B
  bf16* WHH10b = (bf16*)(ws + 8388608ull);          //  8,388,608 B
  bf16* OUT7b  = (bf16*)(ws + 16777216ull);         // 33,554,432 B
  bf16* ZERO   = (bf16*)(ws + 50331648ull);         //    262,144 B
  bf16* H2A    = (bf16*)(ws + 50593792ull);         //    262,144 B
  bf16* H2B    = (bf16*)(ws + 50855936ull);         //    262,144 B
  float* C1    = (float*)(ws + 51118080ull);        //    524,288 B
  float* C2    = (float*)(ws + 51642368ull);        //    524,288 B

  // Adaptive workspace: prefer the bf16 pre-convert region (83.9 MB), then
  // as many Xc chunk timesteps as fit.
  const size_t small_bytes = 52166656ull;
  size_t avail = (ws_size > small_bytes) ? (ws_size - small_bytes) : 0;
  const size_t bf_bytes = 83886080ull;   // IN0b 32M + IN4b 32M + WIHb 16M
  int TC = 16, use_bf = 0;
  if (avail >= bf_bytes + 2097152ull) {
    use_bf = 1;
    const size_t a2 = avail - bf_bytes;
    while (TC > 1 && (size_t)TC * 2097152ull > a2) TC >>= 1;
  } else {
    while (TC > 1 && (size_t)TC * 2097152ull > avail) TC >>= 1;
  }
  const int NCH = 128 / TC;
  float* Xc  = (float*)(ws + small_bytes);                         // TC*2 MB
  bf16* IN0b = (bf16*)(ws + small_bytes + (size_t)TC * 2097152ull);
  bf16* IN4b = IN0b + 16777216ull;
  bf16* WIHb = IN4b + 16777216ull;

  hipMemsetAsync(ZERO, 0, 262144, stream);
  hipMemsetAsync(C1, 0, 524288, stream);
  hipMemsetAsync(C2, 0, 524288, stream);

  // Recurrent weights -> bf16 (lossless: values are bf16-grid).
  cvt_k<<<2048, 256, 0, stream>>>(w_hh6, WHH6b);
  cvt_k<<<2048, 256, 0, stream>>>(w_hh10, WHH10b);

  float* o1  = (float*)d_out;
  float* o11 = o1 + 16777216;   // [16384][1024] f32
  float* o14 = o1 + 33554432;   // [16384][2048] f32

  const dim3 ggrid(32, TC);

  // ---- Layer 1: x = [input0 | input4], h history -> OUT7b ----
  if (use_bf) {
    cvt_k<<<8192, 256, 0, stream>>>(input0, IN0b);
    cvt_k<<<8192, 256, 0, stream>>>(input4, IN4b);
    cvt_k<<<4096, 256, 0, stream>>>(w_ih6, WIHb);
  }
  for (int ch = 0; ch < NCH; ++ch) {
    gemm_xp<<<ggrid, 256, 0, stream>>>(
        use_bf ? (const void*)IN0b : (const void*)input0, use_bf,
        use_bf ? (const void*)IN4b : (const void*)input4, use_bf,
        use_bf ? (const void*)WIHb : (const void*)w_ih6, use_bf,
        b_ih6, b_hh6, Xc, ch * TC * 128);
    {
      const bf16* p_whh = WHH6b; const float* p_xp = Xc; float* p_c = C1;
      bf16* p_hist = OUT7b; bf16* p_h2a = nullptr; bf16* p_h2b = nullptr;
      const bf16* p_zero = ZERO; const bf16* p_add = nullptr;
      float* p_o11 = nullptr; float* p_o14 = nullptr;
      int p_t0 = ch * TC, p_ns = TC, p_l2 = 0;
      void* args[] = {&p_whh, &p_xp, &p_c, &p_hist, &p_h2a, &p_h2b,
                      &p_zero, &p_add, &p_o11, &p_o14, &p_t0, &p_ns, &p_l2};
      hipLaunchCooperativeKernel((void*)lstm_chunk, dim3(128), dim3(256),
                                 args, 0, stream);
    }
  }

  // ---- Layer 2: x = [out7(bf16) | input4] ----
  if (use_bf) {
    cvt_k<<<4096, 256, 0, stream>>>(w_ih10, WIHb);
  }
  for (int ch = 0; ch < NCH; ++ch) {
    gemm_xp<<<ggrid, 256, 0, stream>>>(
        (const void*)OUT7b, 1,
        use_bf ? (const void*)IN4b : (const void*)input4, use_bf,
        use_bf ? (const void*)WIHb : (const void*)w_ih10, use_bf,
        b_ih10, b_hh10, Xc, ch * TC * 128);
    {
      const bf16* p_whh = WHH10b; const float* p_xp = Xc; float* p_c = C2;
      bf16* p_hist = nullptr; bf16* p_h2a = H2A; bf16* p_h2b = H2B;
      const bf16* p_zero = ZERO; const bf16* p_add = OUT7b;
      float* p_o11 = o11; float* p_o14 = o14;
      int p_t0 = ch * TC, p_ns = TC, p_l2 = 1;
      void* args[] = {&p_whh, &p_xp, &p_c, &p_hist, &p_h2a, &p_h2b,
                      &p_zero, &p_add, &p_o11, &p_o14, &p_t0, &p_ns, &p_l2};
      hipLaunchCooperativeKernel((void*)lstm_chunk, dim3(128), dim3(256),
                                 args, 0, stream);
    }
  }

  finalize_k<<<16384, 256, 0, stream>>>((const float4*)input4, (float4*)d_out, o14);
}

// Round 3
// 6044.112 us; speedup vs baseline: 1.2646x; 1.2246x over previous
//
#include <hip/hip_runtime.h>
#include <hip/hip_bf16.h>
#include <stdint.h>

typedef __hip_bfloat16 bf16;
typedef __attribute__((ext_vector_type(8))) short s16x8;
typedef __attribute__((ext_vector_type(4))) float f32x4;

#define MFMA_BF16 __builtin_amdgcn_mfma_f32_16x16x32_bf16
#define NB 128   // blocks in the recurrent cooperative kernel

// T=128, B=128, H=1024, I=2048. M = T*B = 16384. Gate order i,f,g,o.
// ALL d_in / d_out storage is FLOAT32 (values bf16-quantized by harness).
//
// Workspace layout (fixed base, same as previous round):
//   WHH6b  bf16 [4096][1024] @ 0           ( 8,388,608 B)
//   WHH10b bf16 [4096][1024] @  8,388,608  ( 8,388,608 B)
//   OUT7b  bf16 [16384][1024] @ 16,777,216 (33,554,432 B)  h1 per-step history
//   ZERO   bf16 [131072]     @ 50,331,648  (   262,144 B)
//   H2A    bf16 [131072]     @ 50,593,792  (   262,144 B)  (fallback ping-pong)
//   H2B    bf16 [131072]     @ 50,855,936  (   262,144 B)
//   C1     f32  [131072]     @ 51,118,080  (   524,288 B)
//   C2     f32  [131072]     @ 51,642,368  (   524,288 B)
//   BAR    u32  [1024]       @ 52,166,656  (     4,096 B)  custom grid barrier
//   H2H    bf16 [16384][1024] @ 52,170,752 (33,554,432 B; if ws allows) layer2 h history
//   Xc     f32  [TC*128][4096] after H2H   (TC*2,097,152 B; TC adaptive)
//   IN0b/IN4b/WIHb bf16 after Xc (32M+32M+16M, only if ws allows: use_bf)

__device__ __forceinline__ float sigmoidf_(float x) {
  return 1.0f / (1.0f + __expf(-x));
}
__device__ __forceinline__ float tanhf_(float x) {
  return 2.0f / (1.0f + __expf(-2.0f * x)) - 1.0f;
}

__device__ __forceinline__ s16x8 cvt8(const float* __restrict__ p) {
  s16x8 r;
#pragma unroll
  for (int i = 0; i < 8; i++) {
    bf16 h = __float2bfloat16(p[i]);   // exact: values are bf16-grid
    r[i] = *(const short*)&h;
  }
  return r;
}

// f32 -> bf16 bulk convert; each thread does 8 elements.
__global__ __launch_bounds__(256)
void cvt_k(const float* __restrict__ src, bf16* __restrict__ dst) {
  const size_t i = (size_t)(blockIdx.x * 256 + threadIdx.x) * 8;
  *(s16x8*)(dst + i) = cvt8(src + i);
}

// X[m][n] = sum_k concat(A0,A1)[row_base+m][k] * W[n][k] + b0[n] + b1[n]
// A0/A1: [16384][1024]; W: [4096][2048]. Each operand bf16 (flag=1) or f32.
// X: [TC*128][4096] f32. grid = (32, TC), block 256.
__global__ __launch_bounds__(256)
void gemm_xp(const void* __restrict__ A0, int a0_bf,
             const void* __restrict__ A1, int a1_bf,
             const void* __restrict__ W, int w_bf,
             const float* __restrict__ b0, const float* __restrict__ b1,
             float* __restrict__ X, int row_base)
{
  __shared__ short As[128][32];
  __shared__ short Bs[128][32];
  const int tid = threadIdx.x;
  const int wave = tid >> 6, lane = tid & 63;
  const int lr = lane & 15, lq = lane >> 4;
  const int wm = wave >> 1, wn = wave & 1;
  const int lrow0 = blockIdx.y * 128;          // local row in chunk
  const int grow0 = row_base + lrow0;          // global row in [0,16384)
  const int col0 = blockIdx.x * 128;

  f32x4 acc[4][4];
  const f32x4 z = {0.f, 0.f, 0.f, 0.f};
  for (int i = 0; i < 4; i++)
    for (int j = 0; j < 4; j++) acc[i][j] = z;

  const int sr = tid >> 2;            // 0..63
  const int skk = (tid & 3) * 8;      // 0,8,16,24

  for (int k0 = 0; k0 < 2048; k0 += 32) {
    if (k0 < 1024) {
      if (a0_bf) {
        const bf16* Ab = (const bf16*)A0;
        *(s16x8*)&As[sr][skk]      = *(const s16x8*)(Ab + (size_t)(grow0 + sr) * 1024 + k0 + skk);
        *(s16x8*)&As[sr + 64][skk] = *(const s16x8*)(Ab + (size_t)(grow0 + sr + 64) * 1024 + k0 + skk);
      } else {
        const float* Af = (const float*)A0;
        *(s16x8*)&As[sr][skk]      = cvt8(Af + (size_t)(grow0 + sr) * 1024 + k0 + skk);
        *(s16x8*)&As[sr + 64][skk] = cvt8(Af + (size_t)(grow0 + sr + 64) * 1024 + k0 + skk);
      }
    } else {
      const int ac = k0 - 1024;
      if (a1_bf) {
        const bf16* Ab = (const bf16*)A1;
        *(s16x8*)&As[sr][skk]      = *(const s16x8*)(Ab + (size_t)(grow0 + sr) * 1024 + ac + skk);
        *(s16x8*)&As[sr + 64][skk] = *(const s16x8*)(Ab + (size_t)(grow0 + sr + 64) * 1024 + ac + skk);
      } else {
        const float* Af = (const float*)A1;
        *(s16x8*)&As[sr][skk]      = cvt8(Af + (size_t)(grow0 + sr) * 1024 + ac + skk);
        *(s16x8*)&As[sr + 64][skk] = cvt8(Af + (size_t)(grow0 + sr + 64) * 1024 + ac + skk);
      }
    }
    if (w_bf) {
      const bf16* Wb = (const bf16*)W;
      *(s16x8*)&Bs[sr][skk]      = *(const s16x8*)(Wb + (size_t)(col0 + sr) * 2048 + k0 + skk);
      *(s16x8*)&Bs[sr + 64][skk] = *(const s16x8*)(Wb + (size_t)(col0 + sr + 64) * 2048 + k0 + skk);
    } else {
      const float* Wf = (const float*)W;
      *(s16x8*)&Bs[sr][skk]      = cvt8(Wf + (size_t)(col0 + sr) * 2048 + k0 + skk);
      *(s16x8*)&Bs[sr + 64][skk] = cvt8(Wf + (size_t)(col0 + sr + 64) * 2048 + k0 + skk);
    }
    __syncthreads();
    s16x8 bfrag[4];
    for (int nt = 0; nt < 4; nt++)
      bfrag[nt] = *(const s16x8*)&Bs[wn * 64 + nt * 16 + lr][lq * 8];
    for (int mt = 0; mt < 4; mt++) {
      s16x8 a = *(const s16x8*)&As[wm * 64 + mt * 16 + lr][lq * 8];
      for (int nt = 0; nt < 4; nt++)
        acc[mt][nt] = MFMA_BF16(a, bfrag[nt], acc[mt][nt], 0, 0, 0);
    }
    __syncthreads();
  }

  for (int mt = 0; mt < 4; mt++) {
    const int mbase = lrow0 + wm * 64 + mt * 16 + lq * 4;   // local row
    for (int nt = 0; nt < 4; nt++) {
      const int n = col0 + wn * 64 + nt * 16 + lr;
      const float bias = b0[n] + b1[n];
      for (int r = 0; r < 4; r++)
        X[(size_t)(mbase + r) * 4096 + n] = acc[mt][nt][r] + bias;
    }
  }
}

// Monotonic device-scope grid barrier. target = total arrivals after this
// barrier completes. bar[0] = arrival counter, bar[64] = generation word
// (separate cache lines). All flag ops are SYSTEM-scope atomics (cache-
// bypassing, coherent at the memory-side point). Data (h) is published via
// write-through system-scope stores, ordered by the vmcnt(0) drain below.
// The agent-acquire fence after the spin invalidates L1/L2 as a safety net.
__device__ __forceinline__ void gbar_sync(unsigned* bar, unsigned target) {
  asm volatile("s_waitcnt vmcnt(0)" ::: "memory");   // h stores acked at IF
  __syncthreads();                                    // whole block drained
  if (threadIdx.x == 0) {
    unsigned old = __hip_atomic_fetch_add(&bar[0], 1u, __ATOMIC_RELAXED,
                                          __HIP_MEMORY_SCOPE_SYSTEM);
    if (old == target - 1u) {
      __hip_atomic_store(&bar[64], target, __ATOMIC_RELAXED,
                         __HIP_MEMORY_SCOPE_SYSTEM);
    } else {
      while (__hip_atomic_load(&bar[64], __ATOMIC_RELAXED,
                               __HIP_MEMORY_SCOPE_SYSTEM) < target) {
        __builtin_amdgcn_s_sleep(1);
      }
    }
    __builtin_amdgcn_fence(__ATOMIC_ACQUIRE, "agent");  // waitcnt + cache inv
  }
  __syncthreads();
}

// Persistent cooperative LSTM chunk. NB=128 blocks x 128 threads (2 waves).
// bid&63 = jb (16 gate-cols x 4 gates), bid>>6 = mb (64-row half).
// Wave w owns rows mb*64 + w*32 .. +31 (2 row-tiles x 4 gate accs).
// w_hh slice (4 gates x 16 cols, K=1024) in 128 KB LDS, XOR-swizzled.
// c stays in registers across the whole chunk. h is published via
// system-scope write-through stores; steps separated by gbar_sync.
__global__ __launch_bounds__(128, 1)
void lstm_chunk(const bf16* __restrict__ w_hh,      // [4096][1024] bf16
                const float* __restrict__ xp,       // [TC*128][4096] f32
                float* __restrict__ c_g,            // [128][1024] f32
                bf16* __restrict__ hist,            // per-step h history (or null)
                bf16* __restrict__ h2a, bf16* __restrict__ h2b, // fallback dbuf
                const bf16* __restrict__ zero,
                const bf16* __restrict__ add_base,  // layer2: OUT7b
                float* __restrict__ o11, float* __restrict__ o14,
                unsigned* __restrict__ bar, unsigned gbase,
                int t0, int nsteps, int layer2)
{
  __shared__ __align__(16) char WS[131072];
  const int tid = threadIdx.x;
  const int wave = tid >> 6, lane = tid & 63;
  const int lr = lane & 15, lq = lane >> 4;
  const int jb = blockIdx.x & 63, mb = blockIdx.x >> 6;
  const int j0 = jb * 16;
  const int wrow = mb * 64 + wave * 32;   // wave's 32 rows

  // Stage w_hh slice: LDS row rr = gate*16 + col holds w_hh[gate*1024+j0+col][:].
  // Swizzle: byte ^= (rr&7)<<4 (write and read sides identical).
  for (int i = tid; i < 8192; i += 128) {
    const int rr = i >> 7, ck = i & 127;          // 64 rows x 128 16B-chunks
    const int g = rr >> 4, col = rr & 15;
    const s16x8 v = *(const s16x8*)(w_hh + ((size_t)(g * 1024 + j0 + col) << 10) + (ck << 3));
    *(s16x8*)(WS + (((rr << 11) + (ck << 4)) ^ ((rr & 7) << 4))) = v;
  }

  const int j = j0 + lr;
  const int sw = (lr & 7) << 4;
  int rbg[4];
#pragma unroll
  for (int g = 0; g < 4; g++) rbg[g] = (g * 16 + lr) << 11;

  // c in registers: rows wrow + mt*16 + lq*4 + r, col j
  float creg[2][4];
#pragma unroll
  for (int mt = 0; mt < 2; mt++)
#pragma unroll
    for (int r = 0; r < 4; r++)
      creg[mt][r] = c_g[(wrow + mt * 16 + lq * 4 + r) * 1024 + j];

  __syncthreads();   // WS ready

  for (int tt = 0; tt < nsteps; ++tt) {
    const int t = t0 + tt;
    const bf16* hp;
    bf16* hn;
    if (hist) {            // per-step fresh buffers (no stale-cache hazard)
      hp = (t == 0) ? zero : (hist + ((size_t)(t - 1) << 17));
      hn = hist + ((size_t)t << 17);
    } else {               // fallback ping-pong (relies on barrier cache inv)
      hp = (t == 0) ? zero : ((t & 1) ? h2a : h2b);
      hn = (t & 1) ? h2b : h2a;
    }

    f32x4 acc[2][4];
    const f32x4 z = {0.f, 0.f, 0.f, 0.f};
#pragma unroll
    for (int mt = 0; mt < 2; mt++)
#pragma unroll
      for (int g = 0; g < 4; g++) acc[mt][g] = z;

    const bf16* ap0 = hp + ((size_t)(wrow + lr) << 10) + lq * 8;
#pragma unroll 8
    for (int k0 = 0; k0 < 1024; k0 += 32) {
      const s16x8 a0 = *(const s16x8*)(ap0 + k0);
      const s16x8 a1 = *(const s16x8*)(ap0 + 16384 + k0);   // +16 rows
      const int co = (((k0 >> 3) + lq) << 4) ^ sw;
      s16x8 b[4];
#pragma unroll
      for (int g = 0; g < 4; g++)
        b[g] = *(const s16x8*)(WS + rbg[g] + co);
#pragma unroll
      for (int g = 0; g < 4; g++)
        acc[0][g] = MFMA_BF16(a0, b[g], acc[0][g], 0, 0, 0);
#pragma unroll
      for (int g = 0; g < 4; g++)
        acc[1][g] = MFMA_BF16(a1, b[g], acc[1][g], 0, 0, 0);
    }

    const float* xpt = xp + ((size_t)tt << 19);
#pragma unroll
    for (int mt = 0; mt < 2; mt++) {
#pragma unroll
      for (int r = 0; r < 4; r++) {
        const int b = wrow + mt * 16 + lq * 4 + r;
        const float gi = acc[mt][0][r] + xpt[b * 4096 + j];
        const float gf = acc[mt][1][r] + xpt[b * 4096 + 1024 + j];
        const float gg = acc[mt][2][r] + xpt[b * 4096 + 2048 + j];
        const float go = acc[mt][3][r] + xpt[b * 4096 + 3072 + j];
        const float i_ = sigmoidf_(gi);
        const float f_ = sigmoidf_(gf);
        const float g_ = tanhf_(gg);
        const float o_ = sigmoidf_(go);
        const float cn = f_ * creg[mt][r] + i_ * g_;
        creg[mt][r] = cn;
        const float hv = o_ * tanhf_(cn);
        const int idx = b * 1024 + j;
        // write-through (system-scope) h store: visible at coherence point
        bf16 hb = __float2bfloat16(hv);
        __hip_atomic_store((unsigned short*)(hn + idx),
                           *(unsigned short*)&hb,
                           __ATOMIC_RELAXED, __HIP_MEMORY_SCOPE_SYSTEM);
        if (layer2) {
          const float ov = hv + __bfloat162float(add_base[((size_t)t << 17) + idx]);
          o11[((size_t)t << 17) + idx] = ov;          // out11[t] (f32)
          o14[((size_t)t << 18) + b * 2048 + j] = ov; // out14[t][:, 0:1024]
        }
      }
    }

    if (tt + 1 < nsteps)
      gbar_sync(bar, gbase + (unsigned)(tt + 1) * NB);
  }

#pragma unroll
  for (int mt = 0; mt < 2; mt++)
#pragma unroll
    for (int r = 0; r < 4; r++)
      c_g[(wrow + mt * 16 + lq * 4 + r) * 1024 + j] = creg[mt][r];
}

// out1 = input4 (f32 copy); out14[:, :, 1024:2048] = input4
__global__ __launch_bounds__(256)
void finalize_k(const float4* __restrict__ in4, float4* __restrict__ out1,
                float* __restrict__ out14)
{
  const int ci = blockIdx.x * 256 + threadIdx.x;   // 4,194,304 chunks of 4 f32
  float4 v = in4[ci];
  out1[ci] = v;
  const int flat = ci * 4;
  const int row = flat >> 10, j = flat & 1023;
  *(float4*)&out14[(size_t)row * 2048 + 1024 + j] = v;
}

extern "C" void kernel_launch(void* const* d_in, const int* in_sizes, int n_in,
                              void* d_out, int out_size, void* d_ws, size_t ws_size,
                              hipStream_t stream)
{
  const float* input4 = (const float*)d_in[0];
  const float* input0 = (const float*)d_in[1];
  const float* w_ih6  = (const float*)d_in[2];
  const float* w_hh6  = (const float*)d_in[3];
  const float* b_ih6  = (const float*)d_in[4];
  const float* b_hh6  = (const float*)d_in[5];
  const float* w_ih10 = (const float*)d_in[6];
  const float* w_hh10 = (const float*)d_in[7];
  const float* b_ih10 = (const float*)d_in[8];
  const float* b_hh10 = (const float*)d_in[9];

  char* ws = (char*)d_ws;
  bf16* WHH6b  = (bf16*)(ws);                       //  8,388,608 B
  bf16* WHH10b = (bf16*)(ws + 8388608ull);          //  8,388,608 B
  bf16* OUT7b  = (bf16*)(ws + 16777216ull);         // 33,554,432 B
  bf16* ZERO   = (bf16*)(ws + 50331648ull);         //    262,144 B
  bf16* H2A    = (bf16*)(ws + 50593792ull);         //    262,144 B
  bf16* H2B    = (bf16*)(ws + 50855936ull);         //    262,144 B
  float* C1    = (float*)(ws + 51118080ull);        //    524,288 B
  float* C2    = (float*)(ws + 51642368ull);        //    524,288 B
  unsigned* BAR = (unsigned*)(ws + 52166656ull);    //      4,096 B

  // Adaptive workspace: priority H2H (layer2 per-step history, 32MB) >
  // bf16 pre-convert (84MB) > larger Xc chunk (TC up to 32).
  const size_t base_end = 52170752ull;
  size_t avail = (ws_size > base_end) ? (ws_size - base_end) : 0;
  size_t off = base_end;
  int use_h2h = 0;
  bf16* H2H = nullptr;
  if (avail >= 33554432ull + 2097152ull) {
    use_h2h = 1;
    H2H = (bf16*)(ws + off);
    off += 33554432ull;
    avail -= 33554432ull;
  }
  const size_t bf_bytes = 83886080ull;   // IN0b 32M + IN4b 32M + WIHb 16M
  int TC = 32, use_bf = 0;
  if (avail >= bf_bytes + 2097152ull) {
    use_bf = 1;
    const size_t a2 = avail - bf_bytes;
    while (TC > 1 && (size_t)TC * 2097152ull > a2) TC >>= 1;
  } else {
    while (TC > 1 && (size_t)TC * 2097152ull > avail) TC >>= 1;
  }
  const int NCH = 128 / TC;
  float* Xc  = (float*)(ws + off);                          // TC*2 MB
  bf16* IN0b = (bf16*)(ws + off + (size_t)TC * 2097152ull);
  bf16* IN4b = IN0b + 16777216ull;
  bf16* WIHb = IN4b + 16777216ull;

  hipMemsetAsync(ZERO, 0, 262144, stream);
  hipMemsetAsync(C1, 0, 524288, stream);
  hipMemsetAsync(C2, 0, 524288, stream);
  hipMemsetAsync(BAR, 0, 4096, stream);

  // Recurrent weights -> bf16 (lossless: values are bf16-grid).
  cvt_k<<<2048, 256, 0, stream>>>(w_hh6, WHH6b);
  cvt_k<<<2048, 256, 0, stream>>>(w_hh10, WHH10b);

  float* o1  = (float*)d_out;
  float* o11 = o1 + 16777216;   // [16384][1024] f32
  float* o14 = o1 + 33554432;   // [16384][2048] f32

  const dim3 ggrid(32, TC);
  unsigned gbase = 0;

  // ---- Layer 1: x = [input0 | input4], h history -> OUT7b ----
  if (use_bf) {
    cvt_k<<<8192, 256, 0, stream>>>(input0, IN0b);
    cvt_k<<<8192, 256, 0, stream>>>(input4, IN4b);
    cvt_k<<<4096, 256, 0, stream>>>(w_ih6, WIHb);
  }
  for (int ch = 0; ch < NCH; ++ch) {
    gemm_xp<<<ggrid, 256, 0, stream>>>(
        use_bf ? (const void*)IN0b : (const void*)input0, use_bf,
        use_bf ? (const void*)IN4b : (const void*)input4, use_bf,
        use_bf ? (const void*)WIHb : (const void*)w_ih6, use_bf,
        b_ih6, b_hh6, Xc, ch * TC * 128);
    {
      const bf16* p_whh = WHH6b; const float* p_xp = Xc; float* p_c = C1;
      bf16* p_hist = OUT7b; bf16* p_h2a = nullptr; bf16* p_h2b = nullptr;
      const bf16* p_zero = ZERO; const bf16* p_add = nullptr;
      float* p_o11 = nullptr; float* p_o14 = nullptr;
      unsigned* p_bar = BAR; unsigned p_gb = gbase;
      int p_t0 = ch * TC, p_ns = TC, p_l2 = 0;
      void* args[] = {&p_whh, &p_xp, &p_c, &p_hist, &p_h2a, &p_h2b,
                      &p_zero, &p_add, &p_o11, &p_o14, &p_bar, &p_gb,
                      &p_t0, &p_ns, &p_l2};
      hipLaunchCooperativeKernel((void*)lstm_chunk, dim3(NB), dim3(128),
                                 args, 0, stream);
      gbase += (unsigned)NB * (unsigned)(TC - 1);
    }
  }

  // ---- Layer 2: x = [out7(bf16) | input4] ----
  if (use_bf) {
    cvt_k<<<4096, 256, 0, stream>>>(w_ih10, WIHb);
  }
  for (int ch = 0; ch < NCH; ++ch) {
    gemm_xp<<<ggrid, 256, 0, stream>>>(
        (const void*)OUT7b, 1,
        use_bf ? (const void*)IN4b : (const void*)input4, use_bf,
        use_bf ? (const void*)WIHb : (const void*)w_ih10, use_bf,
        b_ih10, b_hh10, Xc, ch * TC * 128);
    {
      const bf16* p_whh = WHH10b; const float* p_xp = Xc; float* p_c = C2;
      bf16* p_hist = use_h2h ? H2H : nullptr;
      bf16* p_h2a = H2A; bf16* p_h2b = H2B;
      const bf16* p_zero = ZERO; const bf16* p_add = OUT7b;
      float* p_o11 = o11; float* p_o14 = o14;
      unsigned* p_bar = BAR; unsigned p_gb = gbase;
      int p_t0 = ch * TC, p_ns = TC, p_l2 = 1;
      void* args[] = {&p_whh, &p_xp, &p_c, &p_hist, &p_h2a, &p_h2b,
                      &p_zero, &p_add, &p_o11, &p_o14, &p_bar, &p_gb,
                      &p_t0, &p_ns, &p_l2};
      hipLaunchCooperativeKernel((void*)lstm_chunk, dim3(NB), dim3(128),
                                 args, 0, stream);
      gbase += (unsigned)NB * (unsigned)(TC - 1);
    }
  }

  finalize_k<<<16384, 256, 0, stream>>>((const float4*)input4, (float4*)d_out, o14);
}